// Round 2
// baseline (1744.789 us; speedup 1.0000x reference)
//
#include <hip/hip_runtime.h>
#include <cstdint>
#include <cstddef>

// ---------------------------------------------------------------------------
// ClassifierLSTMDeltas on gfx950 — bf16 MFMA pipeline, round 2.
// Shapes: B=4096 T=31 C=768 BD=128 AUG=384 HID=256 H=64 O=12
// Round-2 changes: 128x128 GEMM tiles with register-prefetch pipeline,
// chunked epilogue (sP aliased over staging LDS -> 38KB/block), LN-stats
// bank-conflict fix, k4 pre-gate prefetch.
// ---------------------------------------------------------------------------

typedef short s8v __attribute__((ext_vector_type(8)));   // 8 bf16 (4 VGPR) MFMA frag
typedef float f4v __attribute__((ext_vector_type(4)));   // MFMA acc

__device__ __forceinline__ unsigned short f2bf(float f) {
  union { float f; unsigned int u; } v; v.f = f;
  unsigned int u = v.u;
  return (unsigned short)((u + 0x7fffu + ((u >> 16) & 1u)) >> 16);  // RNE
}
__device__ __forceinline__ float bf2f(unsigned short h) {
  union { unsigned int u; float f; } v; v.u = ((unsigned int)h) << 16;
  return v.f;
}
__device__ __forceinline__ float fsig(float x) {
  return __fdividef(1.f, 1.f + __expf(-x));
}
__device__ __forceinline__ float ftanh(float x) {
  return 1.f - __fdividef(2.f, 1.f + __expf(2.f * x));
}
__device__ __forceinline__ float fgelu(float x) {          // exact gelu (erf)
  return 0.5f * x * (1.f + erff(x * 0.70710678118654752f));
}

// ---- workspace layout (bytes) ---------------------------------------------
#define OFF_W1T   0u            // [384][768] bf16   (cls|delta|acc transposed)
#define OFF_W2T   589824u       // [256][384] bf16   (lin0 transposed)
#define OFF_WIHT  786432u       // [512][256] bf16   (wih_f rows 0-255, wih_r 256-511)
#define OFF_WHHT  1048576u      // [2][256][64] bf16 (whh transposed per dir)
#define OFF_XS    1114112u      // [126976][768] bf16 x_smooth; later reused as PRE [126976][512]
#define OFF_XW    196149248u    // [4096][768] f32 window mean
#define OFF_LL    208732160u    // [4096][12] f32 linear_logits
#define OFF_WIN   208928768u    // [4096][11][128] bf16 lstm window
#define OFF_XAUG  220463104u    // [126976][384] bf16
#define OFF_XLSTM 317980672u    // [126976][256] bf16

// ===========================================================================
// k0: transpose + bf16-convert all GEMM weights into [N][K] layout
// ===========================================================================
__global__ __launch_bounds__(256) void k0_prep(
    const float* __restrict__ cls_w, const float* __restrict__ delta_w,
    const float* __restrict__ acc_w, const float* __restrict__ lin0_w,
    const float* __restrict__ wih_f, const float* __restrict__ wih_r,
    const float* __restrict__ whh_f, const float* __restrict__ whh_r,
    unsigned short* __restrict__ ws) {
  int i = blockIdx.x * 256 + threadIdx.x;        // 557056 total elements
  if (i < 294912) {                              // W1t[n][k], n in [0,384)
    int n = i / 768, k = i - n * 768;
    int seg = n >> 7, nn = n & 127;
    const float* w = seg == 0 ? cls_w : (seg == 1 ? delta_w : acc_w);
    ws[i] = f2bf(w[k * 128 + nn]);
  } else if (i < 393216) {                       // W2t[n][k], n in [0,256), k in [0,384)
    int j = i - 294912;
    int n = j / 384, k = j - n * 384;
    ws[i] = f2bf(lin0_w[k * 256 + n]);
  } else if (i < 524288) {                       // Wiht[n][k], n in [0,512), k in [0,256)
    int j = i - 393216;
    int n = j >> 8, k = j & 255;
    ws[i] = f2bf(n < 256 ? wih_f[k * 256 + n] : wih_r[k * 256 + (n - 256)]);
  } else if (i < 557056) {                       // Whht[d][n][k]
    int j = i - 524288;
    int d = j >> 14, rem = j & 16383;
    int n = rem >> 6, k = rem & 63;
    const float* w = d ? whh_r : whh_f;
    ws[i] = f2bf(w[k * 256 + n]);
  }
}

// ===========================================================================
// k1: EMA scan over T per (b,c); write bf16 x_smooth + fp32 window mean
// ===========================================================================
__global__ __launch_bounds__(256) void k1_ema(
    const float* __restrict__ x, unsigned short* __restrict__ xs,
    float* __restrict__ xw) {
  int gid = blockIdx.x * 256 + threadIdx.x;      // b*768 + c
  int b = gid / 768;
  int c = gid - b * 768;
  size_t base = (size_t)b * 31 * 768 + c;
  float s = x[base];
  xs[base] = f2bf(s);
  float wsum = 0.f;
#pragma unroll
  for (int t = 1; t < 31; ++t) {
    float xv = x[base + t * 768];
    s = s + 0.3f * (xv - s);
    xs[base + t * 768] = f2bf(s);
    if (t >= 10 && t <= 20) wsum += s;
  }
  xw[gid] = wsum * (1.f / 11.f);
}

// ===========================================================================
// k1b: linear_logits = xw_mean @ lin1_w + lin1_b   (one wave per batch row)
// ===========================================================================
__global__ __launch_bounds__(64) void k1b_linlog(
    const float* __restrict__ xw, const float* __restrict__ lin1_w,
    const float* __restrict__ lin1_b, float* __restrict__ ll) {
  int b = blockIdx.x;
  int lane = threadIdx.x;
  float p[12];
#pragma unroll
  for (int o = 0; o < 12; ++o) p[o] = 0.f;
  for (int k = lane; k < 768; k += 64) {
    float xv = xw[b * 768 + k];
    const float* w = lin1_w + k * 12;
#pragma unroll
    for (int o = 0; o < 12; ++o) p[o] += xv * w[o];
  }
#pragma unroll
  for (int o = 0; o < 12; ++o) {
    float v = p[o];
#pragma unroll
    for (int s = 1; s < 64; s <<= 1) v += __shfl_xor(v, s, 64);
    p[o] = v;
  }
  if (lane == 0) {
#pragma unroll
    for (int o = 0; o < 12; ++o) ll[b * 12 + o] = p[o] + lin1_b[o];
  }
}

// ===========================================================================
// GEMM mainloop: 128x128 tile, 4 waves (2x2 of 64x64), BK=64, reg-prefetch
// pipeline. A: [M][K] bf16 row-major, Bt: [N][K] bf16 row-major.
// LDS stride 72 shorts (pad 8). On exit the final barrier has been taken,
// so sA/sB may be reused as epilogue scratch.
// ===========================================================================
template <int KDIM>
__device__ __forceinline__ void gemm128(
    const unsigned short* __restrict__ A, int rowClamp,
    const unsigned short* __restrict__ Bt,
    unsigned short* sA, unsigned short* sB, f4v acc[4][4]) {
  const int tid  = threadIdx.x;
  const int lane = tid & 63;
  const int wv   = tid >> 6;
  const int l15  = lane & 15;
  const int quad = lane >> 4;
  const int mh   = (wv >> 1) * 64;
  const int nh   = (wv & 1) * 64;
  const int kc   = (tid & 7) * 8;
  const int r0   = tid >> 3;

  const unsigned short* ap[4];
  const unsigned short* bp[4];
  unsigned short* la[4];
  unsigned short* lb[4];
#pragma unroll
  for (int c = 0; c < 4; ++c) {
    int row = r0 + c * 32;
    int gr = row < rowClamp ? row : rowClamp;
    ap[c] = A + (size_t)gr * KDIM + kc;
    bp[c] = Bt + (size_t)row * KDIM + kc;
    la[c] = sA + row * 72 + kc;
    lb[c] = sB + row * 72 + kc;
  }
#pragma unroll
  for (int mt = 0; mt < 4; ++mt)
#pragma unroll
    for (int nt = 0; nt < 4; ++nt)
      acc[mt][nt] = (f4v){0.f, 0.f, 0.f, 0.f};

  uint4 ar[4], br[4];
#pragma unroll
  for (int c = 0; c < 4; ++c) ar[c] = *(const uint4*)(ap[c]);
#pragma unroll
  for (int c = 0; c < 4; ++c) br[c] = *(const uint4*)(bp[c]);
#pragma unroll
  for (int c = 0; c < 4; ++c) *(uint4*)(la[c]) = ar[c];
#pragma unroll
  for (int c = 0; c < 4; ++c) *(uint4*)(lb[c]) = br[c];
  __syncthreads();

  constexpr int KT = KDIM / 64;
  for (int kt = 0; kt < KT; ++kt) {
    if (kt + 1 < KT) {                    // issue next tile's loads early
      int ko = (kt + 1) * 64;
#pragma unroll
      for (int c = 0; c < 4; ++c) ar[c] = *(const uint4*)(ap[c] + ko);
#pragma unroll
      for (int c = 0; c < 4; ++c) br[c] = *(const uint4*)(bp[c] + ko);
    }
#pragma unroll
    for (int ks = 0; ks < 2; ++ks) {
      s8v af[4], bfv[4];
#pragma unroll
      for (int mt = 0; mt < 4; ++mt)
        af[mt] = *(const s8v*)(&sA[(mh + mt * 16 + l15) * 72 + ks * 32 + quad * 8]);
#pragma unroll
      for (int nt = 0; nt < 4; ++nt)
        bfv[nt] = *(const s8v*)(&sB[(nh + nt * 16 + l15) * 72 + ks * 32 + quad * 8]);
#pragma unroll
      for (int mt = 0; mt < 4; ++mt)
#pragma unroll
        for (int nt = 0; nt < 4; ++nt)
          acc[mt][nt] = __builtin_amdgcn_mfma_f32_16x16x32_bf16(af[mt], bfv[nt], acc[mt][nt], 0, 0, 0);
    }
    __syncthreads();
    if (kt + 1 < KT) {
#pragma unroll
      for (int c = 0; c < 4; ++c) *(uint4*)(la[c]) = ar[c];
#pragma unroll
      for (int c = 0; c < 4; ++c) *(uint4*)(lb[c]) = br[c];
      __syncthreads();
    }
  }
}

// dump acc rows [lo, lo+nrows) -> sP [nrows][132] fp32
// C layout: global row = mh + mt*16 + quad*4 + r, col = nh + nt*16 + l15
__device__ __forceinline__ void dump_chunk(f4v acc[4][4], float* sP, int lo, int nrows) {
  const int tid  = threadIdx.x;
  const int lane = tid & 63;
  const int wv   = tid >> 6;
  const int l15  = lane & 15;
  const int quad = lane >> 4;
  const int mh   = (wv >> 1) * 64;
  const int nh   = (wv & 1) * 64;
#pragma unroll
  for (int mt = 0; mt < 4; ++mt)
#pragma unroll
    for (int nt = 0; nt < 4; ++nt)
#pragma unroll
      for (int r = 0; r < 4; ++r) {
        int rr = mh + mt * 16 + quad * 4 + r - lo;
        if ((unsigned)rr < (unsigned)nrows)
          sP[rr * 132 + nh + nt * 16 + l15] = acc[mt][nt][r];
      }
}

// time-stencil (reflect-pad derivative streams) + bias + exact GELU
__device__ __forceinline__ float stencil_gelu(const float* sP, int seg, int row, int t,
                                              int col, const float* __restrict__ bias) {
  const float* p = sP + row * 132 + col;
  float v;
  if (seg == 0) {
    v = p[0];
  } else if (seg == 1) {                          // delta: s_t - s_{t-1}; t=0: s0-s1
    v = (t == 0) ? (p[0] - p[132]) : (p[0] - p[-132]);
  } else {                                        // acc: s_t-2s_{t-1}+s_{t-2}; edges reflect
    if (t == 0)      v = p[0] - 2.f * p[132] + p[264];
    else if (t == 1) v = 2.f * (p[0] - p[-132]);
    else             v = p[0] - 2.f * p[-132] + p[-264];
  }
  return fgelu(v + bias[col]);
}

// ===========================================================================
// k2: P = x_smooth @ W_seg -> stencil -> GELU -> LayerNorm(128) -> x_aug
// M-tile = 4 batches x 31 t (=124 rows in a 128 tile); grid (1024, 3)
// Epilogue in two 62-row (2-batch) chunks; sP aliases staging LDS.
// ===========================================================================
__global__ __launch_bounds__(256, 2) void k2_aug(
    const unsigned short* __restrict__ xs, const unsigned short* __restrict__ W1t,
    const float* __restrict__ cls_b, const float* __restrict__ delta_b,
    const float* __restrict__ acc_b,
    const float* __restrict__ g0, const float* __restrict__ be0,
    const float* __restrict__ g1, const float* __restrict__ be1,
    const float* __restrict__ g2, const float* __restrict__ be2,
    unsigned short* __restrict__ xaug) {
  __shared__ __align__(16) char smem[36864 + 640];
  unsigned short* sA = (unsigned short*)smem;
  unsigned short* sB = (unsigned short*)(smem + 18432);
  float* sP  = (float*)smem;                       // 62*132*4 = 32736 <= 36864
  float* sMu = (float*)(smem + 36864);
  float* sRs = sMu + 62;
  int seg = blockIdx.y;
  int rowBase = blockIdx.x * 124;
  f4v acc[4][4];
  gemm128<768>(xs + (size_t)rowBase * 768, 123, W1t + (size_t)seg * 128 * 768, sA, sB, acc);
  const float* bias = seg == 0 ? cls_b : (seg == 1 ? delta_b : acc_b);
  const float* lng  = seg == 0 ? g0 : (seg == 1 ? g1 : g2);
  const float* lnb  = seg == 0 ? be0 : (seg == 1 ? be1 : be2);
  int tid = threadIdx.x;
#pragma unroll
  for (int ck = 0; ck < 2; ++ck) {
    int lo = ck * 62;                              // batch-aligned (62 = 2*31)
    dump_chunk(acc, sP, lo, 62);
    __syncthreads();
    if (tid < 248) {                               // LN stats, cols interleaved q+4i
      int row = tid >> 2, q = tid & 3;
      int t = row % 31;
      float sum = 0.f, ss = 0.f;
      for (int i = 0; i < 32; ++i) {
        float v = stencil_gelu(sP, seg, row, t, q + 4 * i, bias);
        sum += v; ss += v * v;
      }
      sum += __shfl_xor(sum, 1, 64); sum += __shfl_xor(sum, 2, 64);
      ss  += __shfl_xor(ss,  1, 64); ss  += __shfl_xor(ss,  2, 64);
      float mu = sum * (1.f / 128.f);
      if (q == 0) { sMu[row] = mu; sRs[row] = rsqrtf(ss * (1.f / 128.f) - mu * mu + 1e-5f); }
    }
    __syncthreads();
    for (int idx = tid; idx < 62 * 128; idx += 256) {
      int row = idx >> 7, col = idx & 127;
      int t = row % 31;
      float v = stencil_gelu(sP, seg, row, t, col, bias);
      float o = (v - sMu[row]) * sRs[row] * lng[col] + lnb[col];
      xaug[(size_t)(rowBase + lo + row) * 384 + seg * 128 + col] = f2bf(o);
    }
    __syncthreads();
  }
}

// ===========================================================================
// k3: x_lstm = gelu(x_aug @ lin0_w + b) - time_mean; grid (1024, 2)
// ===========================================================================
__global__ __launch_bounds__(256, 2) void k3_lstm_in(
    const unsigned short* __restrict__ xaug, const unsigned short* __restrict__ W2t,
    const float* __restrict__ lin0_b, unsigned short* __restrict__ xlstm) {
  __shared__ __align__(16) char smem[36864 + 1024];
  unsigned short* sA = (unsigned short*)smem;
  unsigned short* sB = (unsigned short*)(smem + 18432);
  float* sP  = (float*)smem;
  float* sCM = (float*)(smem + 36864);             // [2][128]
  int by = blockIdx.y;
  int rowBase = blockIdx.x * 124;
  f4v acc[4][4];
  gemm128<384>(xaug + (size_t)rowBase * 384, 123, W2t + (size_t)by * 128 * 384, sA, sB, acc);
  int tid = threadIdx.x;
#pragma unroll
  for (int ck = 0; ck < 2; ++ck) {
    int lo = ck * 62;
    dump_chunk(acc, sP, lo, 62);
    __syncthreads();
    for (int idx = tid; idx < 62 * 128; idx += 256) {   // gelu + bias in place
      int row = idx >> 7, col = idx & 127;
      sP[row * 132 + col] = fgelu(sP[row * 132 + col] + lin0_b[by * 128 + col]);
    }
    __syncthreads();
    {                                                   // per-(batch,col) time mean
      int bb = tid >> 7, col = tid & 127;
      float s = 0.f;
      for (int tr = 0; tr < 31; ++tr) s += sP[(bb * 31 + tr) * 132 + col];
      sCM[tid] = s * (1.f / 31.f);
    }
    __syncthreads();
    for (int idx = tid; idx < 62 * 128; idx += 256) {
      int row = idx >> 7, col = idx & 127;
      int bb = row >= 31 ? 1 : 0;
      float v = sP[row * 132 + col] - sCM[bb * 128 + col];
      xlstm[(size_t)(rowBase + lo + row) * 256 + by * 128 + col] = f2bf(v);
    }
    __syncthreads();
  }
}

// ===========================================================================
// k3b: pre = x_lstm @ [wih_f|wih_r] + b (per-dir halves); grid (992, 4)
// ===========================================================================
__global__ __launch_bounds__(256, 2) void k3b_pre(
    const unsigned short* __restrict__ xlstm, const unsigned short* __restrict__ Wiht,
    const float* __restrict__ b_f, const float* __restrict__ b_r,
    unsigned short* __restrict__ pre) {
  __shared__ __align__(16) char smem[36864];
  unsigned short* sA = (unsigned short*)smem;
  unsigned short* sB = (unsigned short*)(smem + 18432);
  float* sP = (float*)smem;                        // 64*132*4 = 33792 <= 36864
  int by = blockIdx.y;
  int rowBase = blockIdx.x * 128;
  f4v acc[4][4];
  gemm128<256>(xlstm + (size_t)rowBase * 256, 127, Wiht + (size_t)by * 128 * 256, sA, sB, acc);
  int tid = threadIdx.x;
#pragma unroll
  for (int ck = 0; ck < 2; ++ck) {
    int lo = ck * 64;
    dump_chunk(acc, sP, lo, 64);
    __syncthreads();
    for (int idx = tid; idx < 64 * 128; idx += 256) {
      int row = idx >> 7, col = idx & 127;
      int gcol = by * 128 + col;
      float bias = gcol < 256 ? b_f[gcol] : b_r[gcol - 256];
      pre[(size_t)(rowBase + lo + row) * 512 + gcol] = f2bf(sP[row * 132 + col] + bias);
    }
    __syncthreads();
  }
}

// ===========================================================================
// k4: LSTM recurrence, one block = 16 batches x 1 direction; grid (256, 2)
// per step: gates(16x256) = pre + h(16x64 bf16) @ whh  via MFMA, then fused
// sigmoid/tanh elementwise (c fp32 in registers). Next step's pre gates are
// prefetched into regs during the MFMA phase. Window h -> global.
// ===========================================================================
__global__ __launch_bounds__(256) void k4_lstm(
    const unsigned short* __restrict__ pre, const unsigned short* __restrict__ Whht,
    unsigned short* __restrict__ win) {
  __shared__ unsigned short sW[256 * 72];   // whh^T [n][k] padded
  __shared__ unsigned short sH[16 * 72];    // h bf16 [b][k] padded
  __shared__ float sG[16 * 260];            // gates fp32 [b][col]
  int tid = threadIdx.x;
  int dir = blockIdx.y;
  int b0  = blockIdx.x * 16;
  {                                         // stage whh^T for this dir
    const unsigned short* src = Whht + dir * 16384;
#pragma unroll
    for (int c = 0; c < 8; ++c) {
      int id = tid + c * 256;               // 2048 chunks of 8 bf16
      int row = id >> 3, kc = (id & 7) * 8;
      uint4 v = *(const uint4*)(src + row * 64 + kc);
      *(uint4*)(&sW[row * 72 + kc]) = v;
    }
  }
  for (int i = tid; i < 16 * 72; i += 256) sH[i] = 0;
  __syncthreads();

  const int lane = tid & 63, wv = tid >> 6, l15 = lane & 15, quad = lane >> 4;
  const int eb = tid >> 4, jb = (tid & 15) * 4;   // elementwise: batch, j-quad
  float cs[4] = {0.f, 0.f, 0.f, 0.f};

  // prefetch t=0's pre row
  int tt0 = dir ? 30 : 0;
  const unsigned short* pbase = pre + ((size_t)(b0 + eb) * 31) * 512 + dir * 256;
  ushort4 pi = *(const ushort4*)(pbase + tt0 * 512 + jb);
  ushort4 pf = *(const ushort4*)(pbase + tt0 * 512 + 64 + jb);
  ushort4 pg = *(const ushort4*)(pbase + tt0 * 512 + 128 + jb);
  ushort4 po = *(const ushort4*)(pbase + tt0 * 512 + 192 + jb);

  for (int t = 0; t < 31; ++t) {
    f4v acc[4];
#pragma unroll
    for (int nt = 0; nt < 4; ++nt) acc[nt] = (f4v){0.f, 0.f, 0.f, 0.f};
#pragma unroll
    for (int ks = 0; ks < 2; ++ks) {
      s8v af = *(const s8v*)(&sH[l15 * 72 + ks * 32 + quad * 8]);
#pragma unroll
      for (int nt = 0; nt < 4; ++nt) {
        int n = wv * 64 + nt * 16 + l15;
        s8v bfv = *(const s8v*)(&sW[n * 72 + ks * 32 + quad * 8]);
        acc[nt] = __builtin_amdgcn_mfma_f32_16x16x32_bf16(af, bfv, acc[nt], 0, 0, 0);
      }
    }
#pragma unroll
    for (int nt = 0; nt < 4; ++nt)
#pragma unroll
      for (int r = 0; r < 4; ++r)
        sG[(quad * 4 + r) * 260 + wv * 64 + nt * 16 + l15] = acc[nt][r];

    ushort4 ni, nf, ng, no;                 // prefetch t+1 before the barrier
    if (t < 30) {
      int ttn = dir ? 29 - t : t + 1;
      ni = *(const ushort4*)(pbase + ttn * 512 + jb);
      nf = *(const ushort4*)(pbase + ttn * 512 + 64 + jb);
      ng = *(const ushort4*)(pbase + ttn * 512 + 128 + jb);
      no = *(const ushort4*)(pbase + ttn * 512 + 192 + jb);
    }
    __syncthreads();

    int tt = dir ? 30 - t : t;
    const float* g = &sG[eb * 260];
    float hv[4];
#pragma unroll
    for (int jj = 0; jj < 4; ++jj) {
      int j = jb + jj;
      float vi = g[j]       + bf2f(jj == 0 ? pi.x : jj == 1 ? pi.y : jj == 2 ? pi.z : pi.w);
      float vf = g[64 + j]  + bf2f(jj == 0 ? pf.x : jj == 1 ? pf.y : jj == 2 ? pf.z : pf.w);
      float vg = g[128 + j] + bf2f(jj == 0 ? pg.x : jj == 1 ? pg.y : jj == 2 ? pg.z : pg.w);
      float vo = g[192 + j] + bf2f(jj == 0 ? po.x : jj == 1 ? po.y : jj == 2 ? po.z : po.w);
      float cc = fsig(vf) * cs[jj] + fsig(vi) * ftanh(vg);
      cs[jj] = cc;
      hv[jj] = fsig(vo) * ftanh(cc);
    }
    ushort4 hb;
    hb.x = f2bf(hv[0]); hb.y = f2bf(hv[1]); hb.z = f2bf(hv[2]); hb.w = f2bf(hv[3]);
    *(ushort4*)(&sH[eb * 72 + jb]) = hb;
    if (tt >= 10 && tt <= 20)
      *(ushort4*)(win + ((size_t)(b0 + eb) * 11 + (tt - 10)) * 128 + dir * 64 + jb) = hb;
    if (t < 30) { pi = ni; pf = nf; pg = ng; po = no; }
    __syncthreads();
  }
}

// ===========================================================================
// k5: attention over window + lin2 + gated blend with linear_logits -> d_out
// ===========================================================================
__global__ __launch_bounds__(256) void k5_attn(
    const unsigned short* __restrict__ win, const float* __restrict__ attn_w,
    const float* __restrict__ attn_b, const float* __restrict__ attn_t,
    const float* __restrict__ lin2_w, const float* __restrict__ lin2_b,
    const float* __restrict__ linlog, const float* __restrict__ gate,
    float* __restrict__ out) {
  __shared__ unsigned short sWin[176 * 128];
  __shared__ float sAw[128];
  __shared__ float sSc[176];
  __shared__ float sAtt[16 * 128];
  int tid = threadIdx.x;
  int b0  = blockIdx.x * 16;
#pragma unroll
  for (int c = 0; c < 11; ++c) {              // stage 16 batches x 11 t x 128 ch
    int id = tid + c * 256;
    int row = id >> 4, kc = (id & 15) * 8;
    uint4 v = *(const uint4*)(win + ((size_t)b0 * 11 + row) * 128 + kc);
    *(uint4*)(&sWin[row * 128 + kc]) = v;
  }
  if (tid < 128) sAw[tid] = attn_w[tid];
  __syncthreads();
  if (tid < 176) {                            // scores
    int b = tid / 11, wt = tid - b * 11;
    const unsigned short* w = &sWin[(b * 11 + wt) * 128];
    float dot = 0.f;
    for (int ch = 0; ch < 128; ++ch) dot += bf2f(w[ch]) * sAw[ch];
    float temp = logf(1.f + __expf(attn_t[0])) + 0.001f;
    sSc[tid] = (dot + attn_b[0]) / temp;
  }
  __syncthreads();
  if (tid < 16) {                             // softmax over 11
    float m = -1e30f;
    for (int wt = 0; wt < 11; ++wt) m = fmaxf(m, sSc[tid * 11 + wt]);
    float e[11], sum = 0.f;
    for (int wt = 0; wt < 11; ++wt) { e[wt] = __expf(sSc[tid * 11 + wt] - m); sum += e[wt]; }
    float inv = __fdividef(1.f, sum);
    for (int wt = 0; wt < 11; ++wt) sSc[tid * 11 + wt] = e[wt] * inv;
  }
  __syncthreads();
#pragma unroll
  for (int p = 0; p < 8; ++p) {               // attended (also an output)
    int task = tid + p * 256;
    int b = task >> 7, ch = task & 127;
    float a = 0.f;
    for (int wt = 0; wt < 11; ++wt)
      a += sSc[b * 11 + wt] * bf2f(sWin[(b * 11 + wt) * 128 + ch]);
    sAtt[b * 128 + ch] = a;
    out[49152 + (size_t)(b0 + b) * 128 + ch] = a;
  }
  __syncthreads();
  if (tid < 192) {                            // lstm_logits + gated blend
    int b = tid / 12, o = tid - b * 12;
    float dot = 0.f;
    for (int ch = 0; ch < 128; ++ch) dot += sAtt[b * 128 + ch] * lin2_w[ch * 12 + o];
    dot += lin2_b[o];
    float lin = linlog[(size_t)(b0 + b) * 12 + o];
    float gg = fsig(gate[0]);
    out[(size_t)(b0 + b) * 12 + o] = lin + gg * (dot - lin);
  }
}

// ===========================================================================
extern "C" void kernel_launch(void* const* d_in, const int* in_sizes, int n_in,
                              void* d_out, int out_size, void* d_ws, size_t ws_size,
                              hipStream_t stream) {
  const float* x       = (const float*)d_in[0];
  const float* cls_w   = (const float*)d_in[1];
  const float* cls_b   = (const float*)d_in[2];
  const float* delta_w = (const float*)d_in[3];
  const float* delta_b = (const float*)d_in[4];
  const float* acc_w   = (const float*)d_in[5];
  const float* acc_b   = (const float*)d_in[6];
  const float* cls_g   = (const float*)d_in[7];
  const float* cls_be  = (const float*)d_in[8];
  const float* del_g   = (const float*)d_in[9];
  const float* del_be  = (const float*)d_in[10];
  const float* accg    = (const float*)d_in[11];
  const float* accbe   = (const float*)d_in[12];
  const float* lin0_w  = (const float*)d_in[13];
  const float* lin0_b  = (const float*)d_in[14];
  const float* gate    = (const float*)d_in[15];
  const float* attn_w  = (const float*)d_in[16];
  const float* attn_b  = (const float*)d_in[17];
  const float* attn_t  = (const float*)d_in[18];
  const float* lin1_w  = (const float*)d_in[19];
  const float* lin1_b  = (const float*)d_in[20];
  const float* lin2_w  = (const float*)d_in[21];
  const float* lin2_b  = (const float*)d_in[22];
  const float* wih_f   = (const float*)d_in[23];
  const float* whh_f   = (const float*)d_in[24];
  const float* b_f     = (const float*)d_in[25];
  const float* wih_r   = (const float*)d_in[26];
  const float* whh_r   = (const float*)d_in[27];
  const float* b_r     = (const float*)d_in[28];

  char* ws = (char*)d_ws;
  unsigned short* W1t   = (unsigned short*)(ws + OFF_W1T);
  unsigned short* W2t   = (unsigned short*)(ws + OFF_W2T);
  unsigned short* Wiht  = (unsigned short*)(ws + OFF_WIHT);
  unsigned short* Whht  = (unsigned short*)(ws + OFF_WHHT);
  unsigned short* XS    = (unsigned short*)(ws + OFF_XS);
  unsigned short* PRE   = XS;  // x_smooth dead after k2; reuse region for pre
  float*          XW    = (float*)(ws + OFF_XW);
  float*          LL    = (float*)(ws + OFF_LL);
  unsigned short* WIN   = (unsigned short*)(ws + OFF_WIN);
  unsigned short* XAUG  = (unsigned short*)(ws + OFF_XAUG);
  unsigned short* XLSTM = (unsigned short*)(ws + OFF_XLSTM);
  float* out = (float*)d_out;

  k0_prep<<<2176, 256, 0, stream>>>(cls_w, delta_w, acc_w, lin0_w, wih_f, wih_r,
                                    whh_f, whh_r, (unsigned short*)ws);
  k1_ema<<<12288, 256, 0, stream>>>(x, XS, XW);
  k1b_linlog<<<4096, 64, 0, stream>>>(XW, lin1_w, lin1_b, LL);
  k2_aug<<<dim3(1024, 3), 256, 0, stream>>>(XS, W1t, cls_b, delta_b, acc_b,
                                            cls_g, cls_be, del_g, del_be, accg, accbe, XAUG);
  k3_lstm_in<<<dim3(1024, 2), 256, 0, stream>>>(XAUG, W2t, lin0_b, XLSTM);
  k3b_pre<<<dim3(992, 4), 256, 0, stream>>>(XLSTM, Wiht, b_f, b_r, PRE);
  k4_lstm<<<dim3(256, 2), 256, 0, stream>>>(PRE, Whht, WIN);
  k5_attn<<<256, 256, 0, stream>>>(WIN, attn_w, attn_b, attn_t, lin2_w, lin2_b,
                                   LL, gate, out);
}

// Round 3
// 1128.024 us; speedup vs baseline: 1.5468x; 1.5468x over previous
//
#include <hip/hip_runtime.h>
#include <cstdint>
#include <cstddef>

// ---------------------------------------------------------------------------
// ClassifierLSTMDeltas on gfx950 — bf16 MFMA pipeline, round 3.
// Shapes: B=4096 T=31 C=768 BD=128 AUG=384 HID=256 H=64 O=12
// Round-3: GEMMs use m97-style global_load_lds (width=16) staging — no VGPR
// round-trip (round-2's reg-prefetch spilled: WRITE_SIZE 95MB->1.24GB).
// 128x128 tile, single-buffered 2-barrier K-loop, 32KB staging LDS aliased
// by epilogue scratch (~33KB/block -> 4 blocks/CU).
// ---------------------------------------------------------------------------

typedef short s8v __attribute__((ext_vector_type(8)));   // 8 bf16 (4 VGPR) MFMA frag
typedef float f4v __attribute__((ext_vector_type(4)));   // MFMA acc

#if defined(__has_builtin)
#if __has_builtin(__builtin_amdgcn_global_load_lds)
#define HAVE_GLL 1
#endif
#endif
#ifndef HAVE_GLL
#define HAVE_GLL 0
#endif

__device__ __forceinline__ unsigned short f2bf(float f) {
  union { float f; unsigned int u; } v; v.f = f;
  unsigned int u = v.u;
  return (unsigned short)((u + 0x7fffu + ((u >> 16) & 1u)) >> 16);  // RNE
}
__device__ __forceinline__ float bf2f(unsigned short h) {
  union { unsigned int u; float f; } v; v.u = ((unsigned int)h) << 16;
  return v.f;
}
__device__ __forceinline__ float fsig(float x) {
  return __fdividef(1.f, 1.f + __expf(-x));
}
__device__ __forceinline__ float ftanh(float x) {
  return 1.f - __fdividef(2.f, 1.f + __expf(2.f * x));
}
__device__ __forceinline__ float fgelu(float x) {          // exact gelu (erf)
  return 0.5f * x * (1.f + erff(x * 0.70710678118654752f));
}

// async 16B global->LDS. ldsU is the WAVE-UNIFORM destination base; HW lands
// lane i at ldsU + i*16 (per cdna_hip_programming §5 caveat). g is per-lane.
__device__ __forceinline__ void ld_lds16(const unsigned short* g,
                                         unsigned short* ldsU, int lane) {
#if HAVE_GLL
  __builtin_amdgcn_global_load_lds(
      (__attribute__((address_space(1))) void*)(uintptr_t)(const void*)g,
      (__attribute__((address_space(3))) void*)(unsigned int)(uintptr_t)(void*)ldsU,
      16, 0, 0);
#else
  *(uint4*)(ldsU + lane * 8) = *(const uint4*)g;
#endif
}
__device__ __forceinline__ void wait_vm0() {
#if HAVE_GLL
  __builtin_amdgcn_s_waitcnt(0x0F70);   // vmcnt(0), lgkm/exp unconstrained
#endif
}

// ---- workspace layout (bytes) ---------------------------------------------
#define OFF_W1T   0u            // [384][768] bf16   (cls|delta|acc transposed)
#define OFF_W2T   589824u       // [256][384] bf16   (lin0 transposed)
#define OFF_WIHT  786432u       // [512][256] bf16   (wih_f rows 0-255, wih_r 256-511)
#define OFF_WHHT  1048576u      // [2][256][64] bf16 (whh transposed per dir)
#define OFF_XS    1114112u      // [126976][768] bf16 x_smooth; later reused as PRE [126976][512]
#define OFF_XW    196149248u    // [4096][768] f32 window mean
#define OFF_LL    208732160u    // [4096][12] f32 linear_logits
#define OFF_WIN   208928768u    // [4096][11][128] bf16 lstm window
#define OFF_XAUG  220463104u    // [126976][384] bf16
#define OFF_XLSTM 317980672u    // [126976][256] bf16

// ===========================================================================
// k0: transpose + bf16-convert all GEMM weights into [N][K] layout
// ===========================================================================
__global__ __launch_bounds__(256) void k0_prep(
    const float* __restrict__ cls_w, const float* __restrict__ delta_w,
    const float* __restrict__ acc_w, const float* __restrict__ lin0_w,
    const float* __restrict__ wih_f, const float* __restrict__ wih_r,
    const float* __restrict__ whh_f, const float* __restrict__ whh_r,
    unsigned short* __restrict__ ws) {
  int i = blockIdx.x * 256 + threadIdx.x;        // 557056 total elements
  if (i < 294912) {                              // W1t[n][k], n in [0,384)
    int n = i / 768, k = i - n * 768;
    int seg = n >> 7, nn = n & 127;
    const float* w = seg == 0 ? cls_w : (seg == 1 ? delta_w : acc_w);
    ws[i] = f2bf(w[k * 128 + nn]);
  } else if (i < 393216) {                       // W2t[n][k], n in [0,256), k in [0,384)
    int j = i - 294912;
    int n = j / 384, k = j - n * 384;
    ws[i] = f2bf(lin0_w[k * 256 + n]);
  } else if (i < 524288) {                       // Wiht[n][k], n in [0,512), k in [0,256)
    int j = i - 393216;
    int n = j >> 8, k = j & 255;
    ws[i] = f2bf(n < 256 ? wih_f[k * 256 + n] : wih_r[k * 256 + (n - 256)]);
  } else if (i < 557056) {                       // Whht[d][n][k]
    int j = i - 524288;
    int d = j >> 14, rem = j & 16383;
    int n = rem >> 6, k = rem & 63;
    const float* w = d ? whh_r : whh_f;
    ws[i] = f2bf(w[k * 256 + n]);
  }
}

// ===========================================================================
// k1: EMA scan over T per (b,c); write bf16 x_smooth + fp32 window mean
// ===========================================================================
__global__ __launch_bounds__(256) void k1_ema(
    const float* __restrict__ x, unsigned short* __restrict__ xs,
    float* __restrict__ xw) {
  int gid = blockIdx.x * 256 + threadIdx.x;      // b*768 + c
  int b = gid / 768;
  int c = gid - b * 768;
  size_t base = (size_t)b * 31 * 768 + c;
  float s = x[base];
  xs[base] = f2bf(s);
  float wsum = 0.f;
#pragma unroll
  for (int t = 1; t < 31; ++t) {
    float xv = x[base + t * 768];
    s = s + 0.3f * (xv - s);
    xs[base + t * 768] = f2bf(s);
    if (t >= 10 && t <= 20) wsum += s;
  }
  xw[gid] = wsum * (1.f / 11.f);
}

// ===========================================================================
// k1b: linear_logits = xw_mean @ lin1_w + lin1_b   (one wave per batch row)
// ===========================================================================
__global__ __launch_bounds__(64) void k1b_linlog(
    const float* __restrict__ xw, const float* __restrict__ lin1_w,
    const float* __restrict__ lin1_b, float* __restrict__ ll) {
  int b = blockIdx.x;
  int lane = threadIdx.x;
  float p[12];
#pragma unroll
  for (int o = 0; o < 12; ++o) p[o] = 0.f;
  for (int k = lane; k < 768; k += 64) {
    float xv = xw[b * 768 + k];
    const float* w = lin1_w + k * 12;
#pragma unroll
    for (int o = 0; o < 12; ++o) p[o] += xv * w[o];
  }
#pragma unroll
  for (int o = 0; o < 12; ++o) {
    float v = p[o];
#pragma unroll
    for (int s = 1; s < 64; s <<= 1) v += __shfl_xor(v, s, 64);
    p[o] = v;
  }
  if (lane == 0) {
#pragma unroll
    for (int o = 0; o < 12; ++o) ll[b * 12 + o] = p[o] + lin1_b[o];
  }
}

// ===========================================================================
// GEMM mainloop: 128x128 tile, 4 waves (2x2 of 64x64), BK=64, staging via
// global_load_lds. A: [M][K] bf16 row-major, Bt: [N][K] bf16 row-major.
// LDS tiles UNPADDED row-major stride 64 shorts (global_load_lds constraint).
// Wave wv slice j covers rows wv*32+j*8 .. +7 (8 rows x 128B = one 1KB DMA).
// Exits with a trailing barrier so sA/sB can be reused as epilogue scratch.
// ===========================================================================
template <int KDIM>
__device__ __forceinline__ void gemm128(
    const unsigned short* __restrict__ A, int rowClamp,
    const unsigned short* __restrict__ Bt,
    unsigned short* sA, unsigned short* sB, f4v acc[4][4]) {
  const int tid  = threadIdx.x;
  const int lane = tid & 63;
  const int wv   = tid >> 6;
  const int l15  = lane & 15;
  const int quad = lane >> 4;
  const int mh   = (wv >> 1) * 64;
  const int nh   = (wv & 1) * 64;

  const int srow = wv * 32 + (lane >> 3);   // this lane's staged row (j=0)
  const int scol = (lane & 7) * 8;          // this lane's staged k-chunk
  const unsigned short* aBase[4];
  const unsigned short* bBase[4];
  unsigned short* aDst[4];
  unsigned short* bDst[4];
#pragma unroll
  for (int j = 0; j < 4; ++j) {
    int r = srow + j * 8;
    int ar = r < rowClamp ? r : rowClamp;
    aBase[j] = A + (size_t)ar * KDIM + scol;
    bBase[j] = Bt + (size_t)r * KDIM + scol;
    aDst[j] = sA + (wv * 4 + j) * 512;      // wave-uniform 1KB slice base
    bDst[j] = sB + (wv * 4 + j) * 512;
  }
#pragma unroll
  for (int mt = 0; mt < 4; ++mt)
#pragma unroll
    for (int nt = 0; nt < 4; ++nt)
      acc[mt][nt] = (f4v){0.f, 0.f, 0.f, 0.f};

  constexpr int KT = KDIM / 64;
  for (int kt = 0; kt < KT; ++kt) {
    if (kt) __syncthreads();                // all waves done reading prev tile
    int ko = kt * 64;
#pragma unroll
    for (int j = 0; j < 4; ++j) ld_lds16(aBase[j] + ko, aDst[j], lane);
#pragma unroll
    for (int j = 0; j < 4; ++j) ld_lds16(bBase[j] + ko, bDst[j], lane);
    wait_vm0();
    __syncthreads();
#pragma unroll
    for (int ks = 0; ks < 2; ++ks) {
      s8v af[4], bfv[4];
#pragma unroll
      for (int mt = 0; mt < 4; ++mt)
        af[mt] = *(const s8v*)(&sA[(mh + mt * 16 + l15) * 64 + ks * 32 + quad * 8]);
#pragma unroll
      for (int nt = 0; nt < 4; ++nt)
        bfv[nt] = *(const s8v*)(&sB[(nh + nt * 16 + l15) * 64 + ks * 32 + quad * 8]);
#pragma unroll
      for (int mt = 0; mt < 4; ++mt)
#pragma unroll
        for (int nt = 0; nt < 4; ++nt)
          acc[mt][nt] = __builtin_amdgcn_mfma_f32_16x16x32_bf16(af[mt], bfv[nt], acc[mt][nt], 0, 0, 0);
    }
  }
  __syncthreads();                          // LDS now safe for epilogue reuse
}

// dump acc rows [lo, lo+nrows) -> sP [nrows][pstr] fp32
// C layout: global row = mh + mt*16 + quad*4 + r, col = nh + nt*16 + l15
__device__ __forceinline__ void dump_chunk(f4v acc[4][4], float* sP, int lo,
                                           int nrows, int pstr) {
  const int tid  = threadIdx.x;
  const int lane = tid & 63;
  const int wv   = tid >> 6;
  const int l15  = lane & 15;
  const int quad = lane >> 4;
  const int mh   = (wv >> 1) * 64;
  const int nh   = (wv & 1) * 64;
#pragma unroll
  for (int mt = 0; mt < 4; ++mt)
#pragma unroll
    for (int nt = 0; nt < 4; ++nt)
#pragma unroll
      for (int r = 0; r < 4; ++r) {
        int rr = mh + mt * 16 + quad * 4 + r - lo;
        if ((unsigned)rr < (unsigned)nrows)
          sP[rr * pstr + nh + nt * 16 + l15] = acc[mt][nt][r];
      }
}

// time-stencil (reflect-pad derivative streams) + bias + exact GELU
__device__ __forceinline__ float stencil_gelu(const float* sP, int seg, int row, int t,
                                              int col, const float* __restrict__ bias) {
  const float* p = sP + row * 132 + col;
  float v;
  if (seg == 0) {
    v = p[0];
  } else if (seg == 1) {                          // delta: s_t - s_{t-1}; t=0: s0-s1
    v = (t == 0) ? (p[0] - p[132]) : (p[0] - p[-132]);
  } else {                                        // acc: s_t-2s_{t-1}+s_{t-2}; edges reflect
    if (t == 0)      v = p[0] - 2.f * p[132] + p[264];
    else if (t == 1) v = 2.f * (p[0] - p[-132]);
    else             v = p[0] - 2.f * p[-132] + p[-264];
  }
  return fgelu(v + bias[col]);
}

// ===========================================================================
// k2: P = x_smooth @ W_seg -> stencil -> GELU -> LayerNorm(128) -> x_aug
// M-tile = 4 batches x 31 t (=124 rows in a 128 tile); grid (1024, 3)
// Epilogue in two 62-row (2-batch) chunks; sP aliases staging LDS.
// ===========================================================================
__global__ __launch_bounds__(256) void k2_aug(
    const unsigned short* __restrict__ xs, const unsigned short* __restrict__ W1t,
    const float* __restrict__ cls_b, const float* __restrict__ delta_b,
    const float* __restrict__ acc_b,
    const float* __restrict__ g0, const float* __restrict__ be0,
    const float* __restrict__ g1, const float* __restrict__ be1,
    const float* __restrict__ g2, const float* __restrict__ be2,
    unsigned short* __restrict__ xaug) {
  __shared__ __align__(16) char smem[33280];
  unsigned short* sA = (unsigned short*)smem;            // 16KB
  unsigned short* sB = (unsigned short*)(smem + 16384);  // 16KB
  float* sP  = (float*)smem;                             // 62*132*4 = 32736
  float* sMu = (float*)(smem + 32768);
  float* sRs = sMu + 62;
  int seg = blockIdx.y;
  int rowBase = blockIdx.x * 124;
  f4v acc[4][4];
  gemm128<768>(xs + (size_t)rowBase * 768, 123, W1t + (size_t)seg * 128 * 768, sA, sB, acc);
  const float* bias = seg == 0 ? cls_b : (seg == 1 ? delta_b : acc_b);
  const float* lng  = seg == 0 ? g0 : (seg == 1 ? g1 : g2);
  const float* lnb  = seg == 0 ? be0 : (seg == 1 ? be1 : be2);
  int tid = threadIdx.x;
#pragma unroll
  for (int ck = 0; ck < 2; ++ck) {
    int lo = ck * 62;                              // batch-aligned (62 = 2*31)
    dump_chunk(acc, sP, lo, 62, 132);
    __syncthreads();
    if (tid < 248) {                               // LN stats, cols interleaved q+4i
      int row = tid >> 2, q = tid & 3;
      int t = row % 31;
      float sum = 0.f, ss = 0.f;
      for (int i = 0; i < 32; ++i) {
        float v = stencil_gelu(sP, seg, row, t, q + 4 * i, bias);
        sum += v; ss += v * v;
      }
      sum += __shfl_xor(sum, 1, 64); sum += __shfl_xor(sum, 2, 64);
      ss  += __shfl_xor(ss,  1, 64); ss  += __shfl_xor(ss,  2, 64);
      float mu = sum * (1.f / 128.f);
      if (q == 0) { sMu[row] = mu; sRs[row] = rsqrtf(ss * (1.f / 128.f) - mu * mu + 1e-5f); }
    }
    __syncthreads();
    for (int idx = tid; idx < 62 * 128; idx += 256) {
      int row = idx >> 7, col = idx & 127;
      int t = row % 31;
      float v = stencil_gelu(sP, seg, row, t, col, bias);
      float o = (v - sMu[row]) * sRs[row] * lng[col] + lnb[col];
      xaug[(size_t)(rowBase + lo + row) * 384 + seg * 128 + col] = f2bf(o);
    }
    __syncthreads();
  }
}

// ===========================================================================
// k3: x_lstm = gelu(x_aug @ lin0_w + b) - time_mean; grid (1024, 2)
// ===========================================================================
__global__ __launch_bounds__(256) void k3_lstm_in(
    const unsigned short* __restrict__ xaug, const unsigned short* __restrict__ W2t,
    const float* __restrict__ lin0_b, unsigned short* __restrict__ xlstm) {
  __shared__ __align__(16) char smem[33792];
  unsigned short* sA = (unsigned short*)smem;
  unsigned short* sB = (unsigned short*)(smem + 16384);
  float* sP  = (float*)smem;
  float* sCM = (float*)(smem + 32768);             // [2][128]
  int by = blockIdx.y;
  int rowBase = blockIdx.x * 124;
  f4v acc[4][4];
  gemm128<384>(xaug + (size_t)rowBase * 384, 123, W2t + (size_t)by * 128 * 384, sA, sB, acc);
  int tid = threadIdx.x;
#pragma unroll
  for (int ck = 0; ck < 2; ++ck) {
    int lo = ck * 62;
    dump_chunk(acc, sP, lo, 62, 132);
    __syncthreads();
    for (int idx = tid; idx < 62 * 128; idx += 256) {   // gelu + bias in place
      int row = idx >> 7, col = idx & 127;
      sP[row * 132 + col] = fgelu(sP[row * 132 + col] + lin0_b[by * 128 + col]);
    }
    __syncthreads();
    {                                                   // per-(batch,col) time mean
      int bb = tid >> 7, col = tid & 127;
      float s = 0.f;
      for (int tr = 0; tr < 31; ++tr) s += sP[(bb * 31 + tr) * 132 + col];
      sCM[tid] = s * (1.f / 31.f);
    }
    __syncthreads();
    for (int idx = tid; idx < 62 * 128; idx += 256) {
      int row = idx >> 7, col = idx & 127;
      int bb = row >= 31 ? 1 : 0;
      float v = sP[row * 132 + col] - sCM[bb * 128 + col];
      xlstm[(size_t)(rowBase + lo + row) * 256 + by * 128 + col] = f2bf(v);
    }
    __syncthreads();
  }
}

// ===========================================================================
// k3b: pre = x_lstm @ [wih_f|wih_r] + b (per-dir halves); grid (992, 4)
// ===========================================================================
__global__ __launch_bounds__(256) void k3b_pre(
    const unsigned short* __restrict__ xlstm, const unsigned short* __restrict__ Wiht,
    const float* __restrict__ b_f, const float* __restrict__ b_r,
    unsigned short* __restrict__ pre) {
  __shared__ __align__(16) char smem[32768];
  unsigned short* sA = (unsigned short*)smem;
  unsigned short* sB = (unsigned short*)(smem + 16384);
  float* sP = (float*)smem;                        // 64*128*4 = 32768 exactly
  int by = blockIdx.y;
  int rowBase = blockIdx.x * 128;
  f4v acc[4][4];
  gemm128<256>(xlstm + (size_t)rowBase * 256, 127, Wiht + (size_t)by * 128 * 256, sA, sB, acc);
  int tid = threadIdx.x;
#pragma unroll
  for (int ck = 0; ck < 2; ++ck) {
    int lo = ck * 64;
    dump_chunk(acc, sP, lo, 64, 128);
    __syncthreads();
    for (int idx = tid; idx < 64 * 128; idx += 256) {
      int row = idx >> 7, col = idx & 127;
      int gcol = by * 128 + col;
      float bias = gcol < 256 ? b_f[gcol] : b_r[gcol - 256];
      pre[(size_t)(rowBase + lo + row) * 512 + gcol] = f2bf(sP[row * 128 + col] + bias);
    }
    __syncthreads();
  }
}

// ===========================================================================
// k4: LSTM recurrence, one block = 16 batches x 1 direction; grid (256, 2)
// per step: gates(16x256) = pre + h(16x64 bf16) @ whh  via MFMA, then fused
// sigmoid/tanh elementwise (c fp32 in registers). Next step's pre gates are
// prefetched into regs during the MFMA phase. Window h -> global.
// ===========================================================================
__global__ __launch_bounds__(256) void k4_lstm(
    const unsigned short* __restrict__ pre, const unsigned short* __restrict__ Whht,
    unsigned short* __restrict__ win) {
  __shared__ unsigned short sW[256 * 72];   // whh^T [n][k] padded
  __shared__ unsigned short sH[16 * 72];    // h bf16 [b][k] padded
  __shared__ float sG[16 * 260];            // gates fp32 [b][col]
  int tid = threadIdx.x;
  int dir = blockIdx.y;
  int b0  = blockIdx.x * 16;
  {                                         // stage whh^T for this dir
    const unsigned short* src = Whht + dir * 16384;
#pragma unroll
    for (int c = 0; c < 8; ++c) {
      int id = tid + c * 256;               // 2048 chunks of 8 bf16
      int row = id >> 3, kc = (id & 7) * 8;
      uint4 v = *(const uint4*)(src + row * 64 + kc);
      *(uint4*)(&sW[row * 72 + kc]) = v;
    }
  }
  for (int i = tid; i < 16 * 72; i += 256) sH[i] = 0;
  __syncthreads();

  const int lane = tid & 63, wv = tid >> 6, l15 = lane & 15, quad = lane >> 4;
  const int eb = tid >> 4, jb = (tid & 15) * 4;   // elementwise: batch, j-quad
  float cs[4] = {0.f, 0.f, 0.f, 0.f};

  // prefetch t=0's pre row
  int tt0 = dir ? 30 : 0;
  const unsigned short* pbase = pre + ((size_t)(b0 + eb) * 31) * 512 + dir * 256;
  ushort4 pi = *(const ushort4*)(pbase + tt0 * 512 + jb);
  ushort4 pf = *(const ushort4*)(pbase + tt0 * 512 + 64 + jb);
  ushort4 pg = *(const ushort4*)(pbase + tt0 * 512 + 128 + jb);
  ushort4 po = *(const ushort4*)(pbase + tt0 * 512 + 192 + jb);

  for (int t = 0; t < 31; ++t) {
    f4v acc[4];
#pragma unroll
    for (int nt = 0; nt < 4; ++nt) acc[nt] = (f4v){0.f, 0.f, 0.f, 0.f};
#pragma unroll
    for (int ks = 0; ks < 2; ++ks) {
      s8v af = *(const s8v*)(&sH[l15 * 72 + ks * 32 + quad * 8]);
#pragma unroll
      for (int nt = 0; nt < 4; ++nt) {
        int n = wv * 64 + nt * 16 + l15;
        s8v bfv = *(const s8v*)(&sW[n * 72 + ks * 32 + quad * 8]);
        acc[nt] = __builtin_amdgcn_mfma_f32_16x16x32_bf16(af, bfv, acc[nt], 0, 0, 0);
      }
    }
#pragma unroll
    for (int nt = 0; nt < 4; ++nt)
#pragma unroll
      for (int r = 0; r < 4; ++r)
        sG[(quad * 4 + r) * 260 + wv * 64 + nt * 16 + l15] = acc[nt][r];

    ushort4 ni, nf, ng, no;                 // prefetch t+1 before the barrier
    if (t < 30) {
      int ttn = dir ? 29 - t : t + 1;
      ni = *(const ushort4*)(pbase + ttn * 512 + jb);
      nf = *(const ushort4*)(pbase + ttn * 512 + 64 + jb);
      ng = *(const ushort4*)(pbase + ttn * 512 + 128 + jb);
      no = *(const ushort4*)(pbase + ttn * 512 + 192 + jb);
    }
    __syncthreads();

    int tt = dir ? 30 - t : t;
    const float* g = &sG[eb * 260];
    float hv[4];
#pragma unroll
    for (int jj = 0; jj < 4; ++jj) {
      int j = jb + jj;
      float vi = g[j]       + bf2f(jj == 0 ? pi.x : jj == 1 ? pi.y : jj == 2 ? pi.z : pi.w);
      float vf = g[64 + j]  + bf2f(jj == 0 ? pf.x : jj == 1 ? pf.y : jj == 2 ? pf.z : pf.w);
      float vg = g[128 + j] + bf2f(jj == 0 ? pg.x : jj == 1 ? pg.y : jj == 2 ? pg.z : pg.w);
      float vo = g[192 + j] + bf2f(jj == 0 ? po.x : jj == 1 ? po.y : jj == 2 ? po.z : po.w);
      float cc = fsig(vf) * cs[jj] + fsig(vi) * ftanh(vg);
      cs[jj] = cc;
      hv[jj] = fsig(vo) * ftanh(cc);
    }
    ushort4 hb;
    hb.x = f2bf(hv[0]); hb.y = f2bf(hv[1]); hb.z = f2bf(hv[2]); hb.w = f2bf(hv[3]);
    *(ushort4*)(&sH[eb * 72 + jb]) = hb;
    if (tt >= 10 && tt <= 20)
      *(ushort4*)(win + ((size_t)(b0 + eb) * 11 + (tt - 10)) * 128 + dir * 64 + jb) = hb;
    if (t < 30) { pi = ni; pf = nf; pg = ng; po = no; }
    __syncthreads();
  }
}

// ===========================================================================
// k5: attention over window + lin2 + gated blend with linear_logits -> d_out
// ===========================================================================
__global__ __launch_bounds__(256) void k5_attn(
    const unsigned short* __restrict__ win, const float* __restrict__ attn_w,
    const float* __restrict__ attn_b, const float* __restrict__ attn_t,
    const float* __restrict__ lin2_w, const float* __restrict__ lin2_b,
    const float* __restrict__ linlog, const float* __restrict__ gate,
    float* __restrict__ out) {
  __shared__ unsigned short sWin[176 * 128];
  __shared__ float sAw[128];
  __shared__ float sSc[176];
  __shared__ float sAtt[16 * 128];
  int tid = threadIdx.x;
  int b0  = blockIdx.x * 16;
#pragma unroll
  for (int c = 0; c < 11; ++c) {              // stage 16 batches x 11 t x 128 ch
    int id = tid + c * 256;
    int row = id >> 4, kc = (id & 15) * 8;
    uint4 v = *(const uint4*)(win + ((size_t)b0 * 11 + row) * 128 + kc);
    *(uint4*)(&sWin[row * 128 + kc]) = v;
  }
  if (tid < 128) sAw[tid] = attn_w[tid];
  __syncthreads();
  if (tid < 176) {                            // scores
    int b = tid / 11, wt = tid - b * 11;
    const unsigned short* w = &sWin[(b * 11 + wt) * 128];
    float dot = 0.f;
    for (int ch = 0; ch < 128; ++ch) dot += bf2f(w[ch]) * sAw[ch];
    float temp = logf(1.f + __expf(attn_t[0])) + 0.001f;
    sSc[tid] = (dot + attn_b[0]) / temp;
  }
  __syncthreads();
  if (tid < 16) {                             // softmax over 11
    float m = -1e30f;
    for (int wt = 0; wt < 11; ++wt) m = fmaxf(m, sSc[tid * 11 + wt]);
    float e[11], sum = 0.f;
    for (int wt = 0; wt < 11; ++wt) { e[wt] = __expf(sSc[tid * 11 + wt] - m); sum += e[wt]; }
    float inv = __fdividef(1.f, sum);
    for (int wt = 0; wt < 11; ++wt) sSc[tid * 11 + wt] = e[wt] * inv;
  }
  __syncthreads();
#pragma unroll
  for (int p = 0; p < 8; ++p) {               // attended (also an output)
    int task = tid + p * 256;
    int b = task >> 7, ch = task & 127;
    float a = 0.f;
    for (int wt = 0; wt < 11; ++wt)
      a += sSc[b * 11 + wt] * bf2f(sWin[(b * 11 + wt) * 128 + ch]);
    sAtt[b * 128 + ch] = a;
    out[49152 + (size_t)(b0 + b) * 128 + ch] = a;
  }
  __syncthreads();
  if (tid < 192) {                            // lstm_logits + gated blend
    int b = tid / 12, o = tid - b * 12;
    float dot = 0.f;
    for (int ch = 0; ch < 128; ++ch) dot += sAtt[b * 128 + ch] * lin2_w[ch * 12 + o];
    dot += lin2_b[o];
    float lin = linlog[(size_t)(b0 + b) * 12 + o];
    float gg = fsig(gate[0]);
    out[(size_t)(b0 + b) * 12 + o] = lin + gg * (dot - lin);
  }
}

// ===========================================================================
extern "C" void kernel_launch(void* const* d_in, const int* in_sizes, int n_in,
                              void* d_out, int out_size, void* d_ws, size_t ws_size,
                              hipStream_t stream) {
  const float* x       = (const float*)d_in[0];
  const float* cls_w   = (const float*)d_in[1];
  const float* cls_b   = (const float*)d_in[2];
  const float* delta_w = (const float*)d_in[3];
  const float* delta_b = (const float*)d_in[4];
  const float* acc_w   = (const float*)d_in[5];
  const float* acc_b   = (const float*)d_in[6];
  const float* cls_g   = (const float*)d_in[7];
  const float* cls_be  = (const float*)d_in[8];
  const float* del_g   = (const float*)d_in[9];
  const float* del_be  = (const float*)d_in[10];
  const float* accg    = (const float*)d_in[11];
  const float* accbe   = (const float*)d_in[12];
  const float* lin0_w  = (const float*)d_in[13];
  const float* lin0_b  = (const float*)d_in[14];
  const float* gate    = (const float*)d_in[15];
  const float* attn_w  = (const float*)d_in[16];
  const float* attn_b  = (const float*)d_in[17];
  const float* attn_t  = (const float*)d_in[18];
  const float* lin1_w  = (const float*)d_in[19];
  const float* lin1_b  = (const float*)d_in[20];
  const float* lin2_w  = (const float*)d_in[21];
  const float* lin2_b  = (const float*)d_in[22];
  const float* wih_f   = (const float*)d_in[23];
  const float* whh_f   = (const float*)d_in[24];
  const float* b_f     = (const float*)d_in[25];
  const float* wih_r   = (const float*)d_in[26];
  const float* whh_r   = (const float*)d_in[27];
  const float* b_r     = (const float*)d_in[28];

  char* ws = (char*)d_ws;
  unsigned short* W1t   = (unsigned short*)(ws + OFF_W1T);
  unsigned short* W2t   = (unsigned short*)(ws + OFF_W2T);
  unsigned short* Wiht  = (unsigned short*)(ws + OFF_WIHT);
  unsigned short* Whht  = (unsigned short*)(ws + OFF_WHHT);
  unsigned short* XS    = (unsigned short*)(ws + OFF_XS);
  unsigned short* PRE   = XS;  // x_smooth dead after k2; reuse region for pre
  float*          XW    = (float*)(ws + OFF_XW);
  float*          LL    = (float*)(ws + OFF_LL);
  unsigned short* WIN   = (unsigned short*)(ws + OFF_WIN);
  unsigned short* XAUG  = (unsigned short*)(ws + OFF_XAUG);
  unsigned short* XLSTM = (unsigned short*)(ws + OFF_XLSTM);
  float* out = (float*)d_out;

  k0_prep<<<2176, 256, 0, stream>>>(cls_w, delta_w, acc_w, lin0_w, wih_f, wih_r,
                                    whh_f, whh_r, (unsigned short*)ws);
  k1_ema<<<12288, 256, 0, stream>>>(x, XS, XW);
  k1b_linlog<<<4096, 64, 0, stream>>>(XW, lin1_w, lin1_b, LL);
  k2_aug<<<dim3(1024, 3), 256, 0, stream>>>(XS, W1t, cls_b, delta_b, acc_b,
                                            cls_g, cls_be, del_g, del_be, accg, accbe, XAUG);
  k3_lstm_in<<<dim3(1024, 2), 256, 0, stream>>>(XAUG, W2t, lin0_b, XLSTM);
  k3b_pre<<<dim3(992, 4), 256, 0, stream>>>(XLSTM, Wiht, b_f, b_r, PRE);
  k4_lstm<<<dim3(256, 2), 256, 0, stream>>>(PRE, Whht, WIN);
  k5_attn<<<256, 256, 0, stream>>>(WIN, attn_w, attn_b, attn_t, lin2_w, lin2_b,
                                   LL, gate, out);
}